// Round 8
// baseline (1207.337 us; speedup 1.0000x reference)
//
#include <hip/hip_runtime.h>
#include <math.h>

// ---------------------------------------------------------------------------
// HelmholtzGCN forward. R20: ONE persistent kernel (all six phases fused with
// software grid barriers) to eliminate per-dispatch overhead — the ~90us of
// unattributed time (sum of profiled kernels + fill ~= 120 vs 214.7 wall; no
// kernel ever exceeds 40.5us). Co-residency by construction: 1024 blocks x
// 256 thr, __launch_bounds__(256,4) caps VGPR at 128 (4 blocks/CU), max LDS
// 33KB -> 132KB/CU. Barriers: device-scope acq/rel atomic + threadfence
// (the cooperative-groups mechanism). W1/W2 staged to LDS once per block.
// Phases (verbatim R12 bodies, grid-stride):
//   P1 k_part (+BN tables/zero rows on last block) | P2 k_build | P3 gemm1
//   | P4 conv1 | P5 gemm2 | P6 conv2 + loss reduce on last block.
// memset zeroes barrier counters + bcnt (workspace is re-poisoned per iter).
// ---------------------------------------------------------------------------

#define BN_EPS 1e-5f
#define NB_BKT 512
#define RCAP 4608      // raw per-bucket capacity (mean 4096, ~8 sigma)
#define PSTRIDE 6400   // RCAP + 256*7 max pad (pad-to-8)
#define NBLK 1024      // persistent grid: 4 blocks/CU x 256 CUs

typedef __attribute__((ext_vector_type(8))) short bf16x8;
typedef __attribute__((ext_vector_type(4))) float f32x4;

__device__ inline unsigned short f2b(float f) {
    unsigned u = __float_as_uint(f);
    unsigned r = (u + 0x7fffu + ((u >> 16) & 1u)) >> 16;
    return (unsigned short)r;
}
__device__ inline float b2f_lo(unsigned u) { return __uint_as_float(u << 16); }
__device__ inline float b2f_hi(unsigned u) { return __uint_as_float(u & 0xffff0000u); }
__device__ inline unsigned pk2(float a, float b) {
    return (unsigned)f2b(a) | ((unsigned)f2b(b) << 16);
}
__device__ inline float tanh_fast(float x) {
    float e = __expf(2.0f * x);
    return 1.0f - 2.0f * __builtin_amdgcn_rcpf(e + 1.0f);
}

struct SPart { unsigned h[NB_BKT], gbase[NB_BKT], cur[NB_BKT]; };            // 6 KB
struct SBuild { unsigned hist[256], sc[256], cur[256], pend[256]; };         // 4 KB
struct SG1 { short wb[4][4][64][8]; float cbuf[4][16][65]; };                // 33 KB (max)
struct SG2 { short wb[2][3][64][8]; float cbuf[4][16][49]; };                // 18.7 KB

// Software grid barrier: release-add, acquire-spin. Device-scope atomics +
// threadfence give cross-XCD visibility (Guideline 16 pattern).
__device__ __forceinline__ void gbar(unsigned* bar, int idx) {
    __syncthreads();
    if (threadIdx.x == 0) {
        __threadfence();
        __hip_atomic_fetch_add(&bar[idx], 1u, __ATOMIC_RELEASE, __HIP_MEMORY_SCOPE_AGENT);
        while (__hip_atomic_load(&bar[idx], __ATOMIC_ACQUIRE, __HIP_MEMORY_SCOPE_AGENT) <
               (unsigned)NBLK)
            __builtin_amdgcn_s_sleep(2);
        __threadfence();
    }
    __syncthreads();
}

__global__ __launch_bounds__(256, 4) void k_mega(
    const float* __restrict__ X, const int* __restrict__ src,
    const int* __restrict__ dst, const int* __restrict__ bn,
    const float* __restrict__ W1, const float* __restrict__ b1,
    const float* __restrict__ k2_1, const float* __restrict__ W2,
    const float* __restrict__ b2p, const float* __restrict__ k2_2,
    const float* __restrict__ g1, const float* __restrict__ be1,
    const float* __restrict__ m1, const float* __restrict__ v1,
    const float* __restrict__ g2, const float* __restrict__ be2,
    const float* __restrict__ m2, const float* __restrict__ v2,
    unsigned* __restrict__ bar, unsigned* __restrict__ bcnt,
    unsigned long long* __restrict__ rowinfo, float* __restrict__ dinv,
    float* __restrict__ A1, float* __restrict__ S1, float* __restrict__ A2,
    float* __restrict__ S2, unsigned* __restrict__ qs,
    unsigned* __restrict__ h1, unsigned* __restrict__ x,
    unsigned* __restrict__ h2, unsigned* __restrict__ part,
    float* __restrict__ partial, float* __restrict__ out,
    int n, int e, int nb, int nbkt, float inv_cnt) {
    __shared__ __align__(16) char smem[sizeof(SG1)];
    int t = threadIdx.x;
    int bid = blockIdx.x;
    int lane = t & 63, wave = t >> 6;

    // ================= P1: edge partition (+ BN tables / zero pad rows) ====
    {
        SPart& s = *reinterpret_cast<SPart*>(smem);
        if (bid == NBLK - 1) {  // constants, concurrent with partition
            if (t < 64) {
                float a = g1[t] * rsqrtf(v1[t] + BN_EPS);
                A1[t] = a;
                S1[t] = (b1[t] - m1[t]) * a + be1[t];
            } else if (t < 104) {
                int cc = t - 64;
                float a = g2[cc] * rsqrtf(v2[cc] + BN_EPS);
                A2[cc] = a;
                S2[cc] = (b2p[cc] - m2[cc]) * a + be2[cc];
            } else if (t < 136) {
                h1[(size_t)n * 32u + (t - 104)] = 0u;
            } else if (t < 156) {
                h2[(size_t)n * 20u + (t - 136)] = 0u;
            }
        }
        int chunk = ((e + NBLK - 1) / NBLK + 3) & ~3;
        int c0 = bid * chunk;
        int c1 = min(c0 + chunk, e);
        for (int i = t; i < NB_BKT; i += 256) s.h[i] = 0;
        __syncthreads();
        if (c0 < e) {
            for (int i = c0 + t * 4; i < c1; i += 1024) {
                if (i + 3 < c1) {
                    int4 d = *(const int4*)&dst[i];
                    atomicAdd(&s.h[(unsigned)d.x >> 8], 1u);
                    atomicAdd(&s.h[(unsigned)d.y >> 8], 1u);
                    atomicAdd(&s.h[(unsigned)d.z >> 8], 1u);
                    atomicAdd(&s.h[(unsigned)d.w >> 8], 1u);
                } else {
                    for (int j = i; j < c1; ++j) atomicAdd(&s.h[(unsigned)dst[j] >> 8], 1u);
                }
            }
        }
        __syncthreads();
        for (int i = t; i < NB_BKT; i += 256) {
            unsigned c = s.h[i];
            s.gbase[i] = c ? (i * RCAP + atomicAdd(&bcnt[i], c)) : 0u;
            s.cur[i] = 0;
        }
        __syncthreads();
        if (c0 < e) {
            for (int i = c0 + t * 4; i < c1; i += 1024) {
                if (i + 3 < c1) {
                    int4 sv = *(const int4*)&src[i];
                    int4 d = *(const int4*)&dst[i];
                    unsigned b0 = (unsigned)d.x >> 8, b1_ = (unsigned)d.y >> 8;
                    unsigned b2_ = (unsigned)d.z >> 8, b3 = (unsigned)d.w >> 8;
                    unsigned p0 = s.gbase[b0] + atomicAdd(&s.cur[b0], 1u);
                    unsigned p1 = s.gbase[b1_] + atomicAdd(&s.cur[b1_], 1u);
                    unsigned p2 = s.gbase[b2_] + atomicAdd(&s.cur[b2_], 1u);
                    unsigned p3 = s.gbase[b3] + atomicAdd(&s.cur[b3], 1u);
                    if (p0 < (b0 + 1) * RCAP)
                        part[p0] = (((unsigned)d.x & 255u) << 24) | (unsigned)sv.x;
                    if (p1 < (b1_ + 1) * RCAP)
                        part[p1] = (((unsigned)d.y & 255u) << 24) | (unsigned)sv.y;
                    if (p2 < (b2_ + 1) * RCAP)
                        part[p2] = (((unsigned)d.z & 255u) << 24) | (unsigned)sv.z;
                    if (p3 < (b3 + 1) * RCAP)
                        part[p3] = (((unsigned)d.w & 255u) << 24) | (unsigned)sv.w;
                } else {
                    for (int j = i; j < c1; ++j) {
                        unsigned b = (unsigned)dst[j] >> 8;
                        unsigned p = s.gbase[b] + atomicAdd(&s.cur[b], 1u);
                        if (p < (b + 1) * RCAP)
                            part[p] = (((unsigned)dst[j] & 255u) << 24) | (unsigned)src[j];
                    }
                }
            }
        }
    }
    gbar(bar, 0);

    // ================= P2: per-bucket build (rowinfo/dinv/qs) ==============
    if (bid < nbkt) {
        SBuild& s = *reinterpret_cast<SBuild*>(smem);
        int b = bid;
        int cnt = (int)min(bcnt[b], (unsigned)RCAP);
        unsigned base = b * RCAP;
        int dst0 = b << 8;
        int nloc = min(256, n - dst0);
        s.hist[t] = 0;
        __syncthreads();
        for (int i = t; i < cnt; i += 256) atomicAdd(&s.hist[part[base + i] >> 24], 1u);
        __syncthreads();
        unsigned c = s.hist[t];
        unsigned pcnt = (t < nloc) ? ((c + 7u) & ~7u) : 0u;
        s.sc[t] = pcnt;
        __syncthreads();
        for (int off = 1; off < 256; off <<= 1) {
            unsigned a = (t >= off) ? s.sc[t - off] : 0u;
            __syncthreads();
            s.sc[t] += a;
            __syncthreads();
        }
        unsigned beg = (unsigned)b * PSTRIDE + (s.sc[t] - pcnt);
        if (t < nloc) {
            rowinfo[dst0 + t] = (unsigned long long)beg | ((unsigned long long)pcnt << 32);
            dinv[dst0 + t] = rsqrtf((float)(c + 1u));
        }
        s.cur[t] = beg;
        s.pend[t] = beg + pcnt;
        __syncthreads();
        for (int i = t; i < cnt; i += 256) {
            unsigned p = part[base + i];
            unsigned pos = atomicAdd(&s.cur[p >> 24], 1u);
            qs[pos] = p & 0xFFFFFFu;
        }
        __syncthreads();
        for (unsigned pos = s.cur[t]; pos < s.pend[t]; ++pos) qs[pos] = (unsigned)n;
    }
    gbar(bar, 1);

    // ================= P3: gemm1 (h1 = dinv * X @ W1, bf16) ================
    {
        SG1& s = *reinterpret_cast<SG1*>(smem);
        for (int sd = t; sd < 1024; sd += 256) {  // stage W1 once
            int l = sd & 63, nt = (sd >> 6) & 3, kt = sd >> 8;
            int kbase = kt * 32 + ((l >> 4) << 3);
            int nn = nt * 16 + (l & 15);
            bf16x8 v;
#pragma unroll
            for (int j = 0; j < 8; ++j) v[j] = (short)f2b(W1[(kbase + j) * 64 + nn]);
            *(bf16x8*)&s.wb[kt][nt][l][0] = v;
        }
        __syncthreads();
        int quad = lane >> 4, m = lane & 15;
        int ntile = (n + 63) >> 6;
        for (int tile = bid; tile < ntile; tile += NBLK) {
            int r0 = tile * 64 + wave * 16;
            f32x4 acc[4];
#pragma unroll
            for (int i = 0; i < 4; ++i) acc[i] = (f32x4){0.f, 0.f, 0.f, 0.f};
            int rr = min(r0 + m, n - 1);
            const float* xrow = X + (size_t)rr * 128;
#pragma unroll
            for (int kt = 0; kt < 4; ++kt) {
                int kb = kt * 32 + quad * 8;
                float4 x0 = *(const float4*)&xrow[kb];
                float4 x1 = *(const float4*)&xrow[kb + 4];
                bf16x8 af;
                af[0] = (short)f2b(x0.x); af[1] = (short)f2b(x0.y);
                af[2] = (short)f2b(x0.z); af[3] = (short)f2b(x0.w);
                af[4] = (short)f2b(x1.x); af[5] = (short)f2b(x1.y);
                af[6] = (short)f2b(x1.z); af[7] = (short)f2b(x1.w);
#pragma unroll
                for (int nt = 0; nt < 4; ++nt) {
                    bf16x8 bf = *(bf16x8*)&s.wb[kt][nt][lane][0];
                    acc[nt] = __builtin_amdgcn_mfma_f32_16x16x32_bf16(af, bf, acc[nt], 0, 0, 0);
                }
            }
#pragma unroll
            for (int nt = 0; nt < 4; ++nt)
#pragma unroll
                for (int r = 0; r < 4; ++r)
                    s.cbuf[wave][quad * 4 + r][nt * 16 + m] = acc[nt][r];
            __syncthreads();
#pragma unroll
            for (int i = 0; i < 8; ++i) {
                int f = i * 64 + lane;
                int row = f >> 5, cp = f & 31;
                int grow = tile * 64 + (t >> 6) * 16 + row;
                if (grow < n) {
                    float dv = dinv[grow];
                    h1[(size_t)grow * 32 + cp] =
                        pk2(dv * s.cbuf[wave][row][2 * cp], dv * s.cbuf[wave][row][2 * cp + 1]);
                }
            }
            __syncthreads();
        }
    }
    gbar(bar, 2);

    // ================= P4: conv1 (gather + BN + tanh + loss partials) ======
    {
        float* red = reinterpret_cast<float*>(smem);
        int quarter = lane >> 4, cl = lane & 15;
        int ng = (n + 15) >> 4;
        for (int g = bid; g < ng; g += NBLK) {
            int node = g * 16 + wave * 4 + quarter;
            float r2 = 0.0f;
            if (node < n) {
                unsigned long long ri = rowinfo[node];
                unsigned beg = (unsigned)ri, pdeg = (unsigned)(ri >> 32);
                float dd = dinv[node];
                float rdd = __builtin_amdgcn_rcpf(dd);
                uint2 hp = *(const uint2*)&h1[(unsigned)node * 32u + 2u * cl];
                float a0 = b2f_lo(hp.x), a1 = b2f_hi(hp.x);
                float a2 = b2f_lo(hp.y), a3 = b2f_hi(hp.y);
                float h0 = a0 * rdd, h1v = a1 * rdd, h2v = a2 * rdd, h3 = a3 * rdd;
                for (unsigned eb = 0; eb < pdeg; eb += 8) {
                    uint4 q0 = *(const uint4*)&qs[beg + eb];
                    uint4 q1 = *(const uint4*)&qs[beg + eb + 4];
                    uint2 p0 = *(const uint2*)&h1[(q0.x << 5) + 2u * cl];
                    uint2 p1 = *(const uint2*)&h1[(q0.y << 5) + 2u * cl];
                    uint2 p2 = *(const uint2*)&h1[(q0.z << 5) + 2u * cl];
                    uint2 p3 = *(const uint2*)&h1[(q0.w << 5) + 2u * cl];
                    uint2 p4 = *(const uint2*)&h1[(q1.x << 5) + 2u * cl];
                    uint2 p5 = *(const uint2*)&h1[(q1.y << 5) + 2u * cl];
                    uint2 p6 = *(const uint2*)&h1[(q1.z << 5) + 2u * cl];
                    uint2 p7 = *(const uint2*)&h1[(q1.w << 5) + 2u * cl];
                    a0 += b2f_lo(p0.x); a1 += b2f_hi(p0.x);
                    a2 += b2f_lo(p0.y); a3 += b2f_hi(p0.y);
                    a0 += b2f_lo(p1.x); a1 += b2f_hi(p1.x);
                    a2 += b2f_lo(p1.y); a3 += b2f_hi(p1.y);
                    a0 += b2f_lo(p2.x); a1 += b2f_hi(p2.x);
                    a2 += b2f_lo(p2.y); a3 += b2f_hi(p2.y);
                    a0 += b2f_lo(p3.x); a1 += b2f_hi(p3.x);
                    a2 += b2f_lo(p3.y); a3 += b2f_hi(p3.y);
                    a0 += b2f_lo(p4.x); a1 += b2f_hi(p4.x);
                    a2 += b2f_lo(p4.y); a3 += b2f_hi(p4.y);
                    a0 += b2f_lo(p5.x); a1 += b2f_hi(p5.x);
                    a2 += b2f_lo(p5.y); a3 += b2f_hi(p5.y);
                    a0 += b2f_lo(p6.x); a1 += b2f_hi(p6.x);
                    a2 += b2f_lo(p6.y); a3 += b2f_hi(p6.y);
                    a0 += b2f_lo(p7.x); a1 += b2f_hi(p7.x);
                    a2 += b2f_lo(p7.y); a3 += b2f_hi(p7.y);
                }
                float k2 = k2_1[0];
                float g0 = dd * a0, g1v = dd * a1, g2v = dd * a2, g3 = dd * a3;
                float r0 = g0 + (k2 - 1.0f) * h0, r1 = g1v + (k2 - 1.0f) * h1v;
                float r2c = g2v + (k2 - 1.0f) * h2v, r3 = g3 + (k2 - 1.0f) * h3;
                r2 = r0 * r0 + r1 * r1 + r2c * r2c + r3 * r3;
                float4 Ap = *(const float4*)&A1[4 * cl];
                float4 Sp = *(const float4*)&S1[4 * cl];
                float x0 = tanh_fast((g0 + k2 * h0) * Ap.x + Sp.x);
                float x1 = tanh_fast((g1v + k2 * h1v) * Ap.y + Sp.y);
                float x2 = tanh_fast((g2v + k2 * h2v) * Ap.z + Sp.z);
                float x3 = tanh_fast((g3 + k2 * h3) * Ap.w + Sp.w);
                uint2 o;
                o.x = pk2(x0, x1);
                o.y = pk2(x2, x3);
                *(uint2*)&x[(unsigned)node * 32u + 2u * cl] = o;
            }
            for (int off = 32; off; off >>= 1) r2 += __shfl_xor(r2, off, 64);
            if (lane == 0) red[wave] = r2;
            __syncthreads();
            if (t == 0) partial[g] = red[0] + red[1] + red[2] + red[3];
            __syncthreads();
        }
    }
    gbar(bar, 3);

    // ================= P5: gemm2 (h2 = dinv * x @ W2, bf16) ================
    {
        SG2& s = *reinterpret_cast<SG2*>(smem);
        for (int sd = t; sd < 384; sd += 256) {  // stage W2 once
            int l = sd & 63, nt = (sd >> 6) % 3, kt = sd / 192;
            int kbase = kt * 32 + ((l >> 4) << 3);
            int c = nt * 16 + (l & 15);
            bf16x8 v;
#pragma unroll
            for (int j = 0; j < 8; ++j)
                v[j] = (c < 40) ? (short)f2b(W2[(kbase + j) * 40 + c]) : (short)0;
            *(bf16x8*)&s.wb[kt][nt][l][0] = v;
        }
        __syncthreads();
        int quad = lane >> 4, m = lane & 15;
        int ntile = (n + 63) >> 6;
        const unsigned short* Xb = (const unsigned short*)x;
        for (int tile = bid; tile < ntile; tile += NBLK) {
            int r0 = tile * 64 + wave * 16;
            f32x4 acc[3];
#pragma unroll
            for (int i = 0; i < 3; ++i) acc[i] = (f32x4){0.f, 0.f, 0.f, 0.f};
            int rr = min(r0 + m, n - 1);
            const unsigned short* xrow = Xb + (size_t)rr * 64;
#pragma unroll
            for (int kt = 0; kt < 2; ++kt) {
                bf16x8 af = *(const bf16x8*)&xrow[kt * 32 + quad * 8];
#pragma unroll
                for (int nt = 0; nt < 3; ++nt) {
                    bf16x8 bf = *(bf16x8*)&s.wb[kt][nt][lane][0];
                    acc[nt] = __builtin_amdgcn_mfma_f32_16x16x32_bf16(af, bf, acc[nt], 0, 0, 0);
                }
            }
#pragma unroll
            for (int nt = 0; nt < 3; ++nt)
#pragma unroll
                for (int r = 0; r < 4; ++r)
                    s.cbuf[wave][quad * 4 + r][nt * 16 + m] = acc[nt][r];
            __syncthreads();
#pragma unroll
            for (int i = 0; i < 5; ++i) {
                int f = i * 64 + lane;
                int row = f / 20, cp = f % 20;
                int grow = tile * 64 + wave * 16 + row;
                if (grow < n) {
                    float dv = dinv[grow];
                    h2[(size_t)grow * 20 + cp] =
                        pk2(dv * s.cbuf[wave][row][2 * cp], dv * s.cbuf[wave][row][2 * cp + 1]);
                }
            }
            __syncthreads();
        }
    }
    gbar(bar, 4);

    // ================= P6: conv2 + log_softmax; last block reduces loss ====
    if (bid == NBLK - 1) {
        float* red = reinterpret_cast<float*>(smem);
        int ng1 = (n + 15) >> 4;
        float ssum = 0.f;
        for (int i = t; i < ng1; i += 256) ssum += partial[i];
        for (int off = 32; off; off >>= 1) ssum += __shfl_xor(ssum, off, 64);
        if (lane == 0) red[wave] = ssum;
        __syncthreads();
        if (t == 0) out[(size_t)nb * 40] = (red[0] + red[1] + red[2] + red[3]) * inv_cnt;
    } else {
        int half = lane >> 5, p32 = lane & 31;
        unsigned p = (unsigned)min(p32, 19);
        int ng2 = (nb + 7) >> 3;
        for (int g = bid; g < ng2; g += NBLK - 1) {
            int wid = g * 8 + wave * 2 + half;
            if (wid < nb) {
                int node = bn[wid];
                unsigned long long ri = rowinfo[node];
                unsigned beg = (unsigned)ri, pdeg = (unsigned)(ri >> 32);
                float dd = dinv[node];
                float rdd = __builtin_amdgcn_rcpf(dd);
                unsigned hp = h2[(unsigned)node * 20u + p];
                float ax = b2f_lo(hp), ay = b2f_hi(hp);
                float hx = ax * rdd, hy = ay * rdd;
                for (unsigned eb = 0; eb < pdeg; eb += 8) {
                    uint4 q0 = *(const uint4*)&qs[beg + eb];
                    uint4 q1 = *(const uint4*)&qs[beg + eb + 4];
                    unsigned pv0 = h2[q0.x * 20u + p];
                    unsigned pv1 = h2[q0.y * 20u + p];
                    unsigned pv2 = h2[q0.z * 20u + p];
                    unsigned pv3 = h2[q0.w * 20u + p];
                    unsigned pv4 = h2[q1.x * 20u + p];
                    unsigned pv5 = h2[q1.y * 20u + p];
                    unsigned pv6 = h2[q1.z * 20u + p];
                    unsigned pv7 = h2[q1.w * 20u + p];
                    ax += b2f_lo(pv0); ay += b2f_hi(pv0);
                    ax += b2f_lo(pv1); ay += b2f_hi(pv1);
                    ax += b2f_lo(pv2); ay += b2f_hi(pv2);
                    ax += b2f_lo(pv3); ay += b2f_hi(pv3);
                    ax += b2f_lo(pv4); ay += b2f_hi(pv4);
                    ax += b2f_lo(pv5); ay += b2f_hi(pv5);
                    ax += b2f_lo(pv6); ay += b2f_hi(pv6);
                    ax += b2f_lo(pv7); ay += b2f_hi(pv7);
                }
                float k2 = k2_2[0];
                float2 Ap = *(const float2*)&A2[2 * p];
                float2 Sp = *(const float2*)&S2[2 * p];
                float tx = tanh_fast((dd * ax + k2 * hx) * Ap.x + Sp.x);
                float ty = tanh_fast((dd * ay + k2 * hy) * Ap.y + Sp.y);
                bool act = (p32 < 20);
                float mx = act ? fmaxf(tx, ty) : -INFINITY;
                for (int off = 16; off; off >>= 1) mx = fmaxf(mx, __shfl_xor(mx, off, 32));
                float es = act ? (__expf(tx - mx) + __expf(ty - mx)) : 0.f;
                for (int off = 16; off; off >>= 1) es += __shfl_xor(es, off, 32);
                if (act) {
                    float ls = mx + __logf(es);
                    float2 o = make_float2(tx - ls, ty - ls);
                    *(float2*)&out[(size_t)wid * 40 + 2 * p] = o;
                }
            }
        }
    }
}

extern "C" void kernel_launch(void* const* d_in, const int* in_sizes, int n_in,
                              void* d_out, int out_size, void* d_ws, size_t ws_size,
                              hipStream_t stream) {
    const float* features = (const float*)d_in[0];
    const int* edge_index = (const int*)d_in[1];
    const int* batch_nodes = (const int*)d_in[2];
    const float* W1 = (const float*)d_in[3];
    const float* b1 = (const float*)d_in[4];
    const float* k2_1 = (const float*)d_in[5];
    const float* W2 = (const float*)d_in[6];
    const float* b2 = (const float*)d_in[7];
    const float* k2_2 = (const float*)d_in[8];
    const float* g1 = (const float*)d_in[9];
    const float* be1 = (const float*)d_in[10];
    const float* m1 = (const float*)d_in[11];
    const float* v1 = (const float*)d_in[12];
    const float* g2 = (const float*)d_in[13];
    const float* be2 = (const float*)d_in[14];
    const float* m2 = (const float*)d_in[15];
    const float* v2 = (const float*)d_in[16];

    const int N = in_sizes[0] / 128;
    const int E = in_sizes[1] / 2;
    const int NB = in_sizes[2];
    const int* src = edge_index;
    const int* dst = edge_index + E;
    const int NBKT = (N + 255) >> 8;   // <= 512
    const int NG1 = (N + 15) / 16;

    unsigned* ws = (unsigned*)d_ws;
    auto align64 = [](size_t o) { return (o + 63) & ~(size_t)63; };
    size_t o = 0;
    unsigned* bar = ws + o;               o = align64(o + 16);
    unsigned* bcnt = ws + o;              o = align64(o + NB_BKT);
    unsigned long long* rowinfo = (unsigned long long*)(ws + o); o = align64(o + 2 * (size_t)N);
    float* dinv = (float*)(ws + o);       o = align64(o + N);
    float* A1 = (float*)(ws + o);         o = align64(o + 64);
    float* S1 = (float*)(ws + o);         o = align64(o + 64);
    float* A2 = (float*)(ws + o);         o = align64(o + 64);
    float* S2 = (float*)(ws + o);         o = align64(o + 64);
    float* partial = (float*)(ws + o);    o = align64(o + NG1);
    unsigned* qs = ws + o;                o = align64(o + (size_t)NB_BKT * PSTRIDE);
    unsigned* h1 = ws + o;                o = align64(o + (size_t)(N + 1) * 32);
    unsigned* x = ws + o;                 o = align64(o + (size_t)N * 32);
    unsigned* h2 = ws + o;                o = align64(o + (size_t)(N + 1) * 20);
    unsigned* part = ws + o;              o = align64(o + (size_t)NB_BKT * RCAP);

    // zero barrier counters + bucket reservations (workspace is poisoned
    // between iterations, so this must run every launch)
    hipMemsetAsync(ws, 0, (16 + NB_BKT) * sizeof(unsigned), stream);
    k_mega<<<NBLK, 256, 0, stream>>>(features, src, dst, batch_nodes, W1, b1,
                                     k2_1, W2, b2, k2_2, g1, be1, m1, v1, g2,
                                     be2, m2, v2, bar, bcnt, rowinfo, dinv, A1,
                                     S1, A2, S2, qs, h1, x, h2, part, partial,
                                     (float*)d_out, N, E, NB, NBKT,
                                     1.0f / ((float)N * 64.0f));
}